// Round 11
// baseline (180.964 us; speedup 1.0000x reference)
//
#include <hip/hip_runtime.h>
#include <math.h>

// DeepIRT forward. Dims from the reference:
#define B_   64
#define T_   256
#define M_   64
#define DK_  128
#define DV_  256
#define S_   128
#define NQR  201     // Eq rows  (q_data in [0,200])
#define NQAR 401     // Eqa rows (qa_data in [0,400])
#define NSR  2001    // Es rows  (s_data in [0,2000])

typedef float f2 __attribute__((ext_vector_type(2)));

static __device__ __forceinline__ int imin(int a, int b){ return a < b ? a : b; }

static __device__ __forceinline__ float fast_tanh(float x){
  float e = __expf(2.f * x);
  return 1.f - 2.f / (e + 1.f);
}

// ---------------------------------------------------------------------------
// DPP adds (GCNDPPCombine folds mov+add into v_add_f32_dpp).
// ---------------------------------------------------------------------------
template<int CTRL, int RM>
static __device__ __forceinline__ float dppadd(float x) {
  return x + __int_as_float(
      __builtin_amdgcn_update_dpp(0, __float_as_int(x), CTRL, RM, 0xf, true));
}
// full wave64 sum -> lane 63
static __device__ __forceinline__ float wave_sum_lane63(float x) {
  x = dppadd<0x111, 0xf>(x);
  x = dppadd<0x112, 0xf>(x);
  x = dppadd<0x114, 0xf>(x);
  x = dppadd<0x118, 0xf>(x);
  x = dppadd<0x142, 0xa>(x);  // row_bcast:15
  x = dppadd<0x143, 0xc>(x);  // row_bcast:31
  return x;
}

// ---------------------------------------------------------------------------
// Role: corr row + fused w2/csb rows.  4 rows/block, 1 wave/row.
// ---------------------------------------------------------------------------
__device__ void corr_role(int blk, const float* __restrict__ Eq,
                          const float* __restrict__ Km,
                          const float* __restrict__ Wsa,
                          const float* __restrict__ bsa,
                          float* __restrict__ corr,
                          float* __restrict__ w2_t,
                          float* __restrict__ csb_t)
{
  __shared__ float eq[4][DK_];
  __shared__ float cwb[4][M_];
  const int w = threadIdx.x >> 6, m = threadIdx.x & 63;
  const int i  = blk * 4 + w;
  const int ic = imin(i, NQR - 1);
  eq[w][m]      = Eq[ic * DK_ + m];
  eq[w][m + 64] = Eq[ic * DK_ + 64 + m];
  float acc = 0.f;
  const float4* kr = (const float4*)(Km + m * DK_);
  #pragma unroll 8
  for (int k4 = 0; k4 < DK_ / 4; ++k4) {
    float4 kv = kr[k4];
    acc = fmaf(eq[w][k4 * 4 + 0], kv.x, acc);
    acc = fmaf(eq[w][k4 * 4 + 1], kv.y, acc);
    acc = fmaf(eq[w][k4 * 4 + 2], kv.z, acc);
    acc = fmaf(eq[w][k4 * 4 + 3], kv.w, acc);
  }
  float mx = acc;
  #pragma unroll
  for (int off = 32; off; off >>= 1) mx = fmaxf(mx, __shfl_xor(mx, off, 64));
  float e = __expf(acc - mx);
  float ssum = e;
  #pragma unroll
  for (int off = 32; off; off >>= 1) ssum += __shfl_xor(ssum, off, 64);
  const float cw = e / ssum;
  if (i < NQR) corr[i * M_ + m] = cw;
  cwb[w][m] = cw;

  float pv = wave_sum_lane63(cw * bsa[m]);
  if (m == 63 && i < NQR) csb_t[i] = pv;

  float aw[4] = {0,0,0,0};
  for (int mm4 = 0; mm4 < M_ / 4; ++mm4) {
    #pragma unroll
    for (int r = 0; r < 4; ++r) {
      float4 wv = *(const float4*)(Wsa + (r * 64 + m) * M_ + mm4 * 4);
      aw[r] = fmaf(cwb[w][mm4 * 4 + 0], wv.x, aw[r]);
      aw[r] = fmaf(cwb[w][mm4 * 4 + 1], wv.y, aw[r]);
      aw[r] = fmaf(cwb[w][mm4 * 4 + 2], wv.z, aw[r]);
      aw[r] = fmaf(cwb[w][mm4 * 4 + 3], wv.w, aw[r]);
    }
  }
  if (i < NQR) {
    #pragma unroll
    for (int r = 0; r < 4; ++r) w2_t[i * DV_ + r * 64 + m] = aw[r];
  }
}

// ---------------------------------------------------------------------------
// Role: erase/add tables, duplicated-pack: eat2[i][d] = {er, er, ad, ad}
// (one dwordx4 load in the scan yields both packed-broadcast pairs).
// ---------------------------------------------------------------------------
__device__ void ea_role(int blk, const float* __restrict__ Eqa,
                        const float* __restrict__ We, const float* __restrict__ be,
                        const float* __restrict__ Wa, const float* __restrict__ ba,
                        float* __restrict__ eat2)
{
  __shared__ float a[8][DV_];
  const int d  = threadIdx.x;
  const int i0 = blk * 8;
  #pragma unroll
  for (int r = 0; r < 8; ++r) a[r][d] = Eqa[imin(i0 + r, NQAR - 1) * DV_ + d];
  __syncthreads();
  float er[8] = {0,0,0,0,0,0,0,0}, ad[8] = {0,0,0,0,0,0,0,0};
  for (int k = 0; k < DV_; ++k) {
    float we = We[k * DV_ + d];
    float wa = Wa[k * DV_ + d];
    #pragma unroll
    for (int r = 0; r < 8; ++r) {
      er[r] = fmaf(a[r][k], we, er[r]);
      ad[r] = fmaf(a[r][k], wa, ad[r]);
    }
  }
  const float beo = be[d], bao = ba[d];
  #pragma unroll
  for (int r = 0; r < 8; ++r) {
    int i = i0 + r;
    if (i < NQAR) {
      float4 v;
      v.x = er[r] + beo;  v.y = v.x;
      v.z = ad[r] + bao;  v.w = v.z;
      *(float4*)(eat2 + (size_t)(i * DV_ + d) * 4) = v;
    }
  }
}

// ---------------------------------------------------------------------------
// Role: tanh-MLP scalar tables.
// ---------------------------------------------------------------------------
__device__ void mlp_role(int blk, const float* __restrict__ E,
                         const float* __restrict__ W1, const float* __restrict__ b1,
                         const float* __restrict__ W2v, const float* __restrict__ b2,
                         float* __restrict__ outt, int nrows)
{
  __shared__ float e[8 * S_];
  __shared__ float red[8][2];
  const int tid = threadIdx.x;
  const int s = tid & 127, rh = tid >> 7;
  const int i0 = blk * 8;
  #pragma unroll
  for (int j = 0; j < 4; ++j) {
    int x = tid + j * 256;
    int row = imin(i0 + (x >> 7), nrows - 1);
    e[x] = E[row * DK_ + (x & 127)];
  }
  __syncthreads();
  float acc[4] = {0,0,0,0};
  const float* eb = e + rh * 4 * 128;
  for (int k = 0; k < DK_; ++k) {
    float wv = W1[k * S_ + s];
    #pragma unroll
    for (int r = 0; r < 4; ++r) acc[r] = fmaf(eb[r * 128 + k], wv, acc[r]);
  }
  const float b1s = b1[s], w2s = W2v[s];
  float p[4];
  #pragma unroll
  for (int r = 0; r < 4; ++r) p[r] = fast_tanh(acc[r] + b1s) * w2s;
  #pragma unroll
  for (int r = 0; r < 4; ++r) p[r] = wave_sum_lane63(p[r]);
  const int lane = tid & 63;
  const int half = s >> 6;
  if (lane == 63) {
    #pragma unroll
    for (int r = 0; r < 4; ++r) red[rh * 4 + r][half] = p[r];
  }
  __syncthreads();
  if (tid < 8) {
    int i = i0 + tid;
    if (i < nrows) outt[i] = red[tid][0] + red[tid][1] + b2[0];
  }
}

// ---------------------------------------------------------------------------
// Role: packed index table pk[b,t] = (qa<<16) | q.  16 blocks x 1024 vals.
// ---------------------------------------------------------------------------
__device__ void pk_role(int blk, const int* __restrict__ q,
                        const int* __restrict__ qa, int* __restrict__ pkt)
{
  const int i = (blk * 256 + threadIdx.x) * 4;
  int4 qv = *(const int4*)(q + i);
  int4 av = *(const int4*)(qa + i);
  int4 p;
  p.x = (av.x << 16) | qv.x;
  p.y = (av.y << 16) | qv.y;
  p.z = (av.z << 16) | qv.z;
  p.w = (av.w << 16) | qv.w;
  *(int4*)(pkt + i) = p;
}

// ---------------------------------------------------------------------------
#define NB_CORR 51
#define NB_EA   51
#define NB_QD   26
#define NB_SD   251
#define NB_PK   16
#define NB_TOT  (NB_CORR + NB_EA + NB_QD + NB_SD + NB_PK)

__global__ __launch_bounds__(256) void tables_kernel(
    const int* q_data, const int* qa_data, int* pkt,
    const float* Eq, const float* Km, const float* Wsa, const float* bsa,
    float* corr_t, float* w2_t, float* csb_t,
    const float* Eqa, const float* We, const float* be,
    const float* Wa, const float* ba, float* eat2,
    const float* Wqd1, const float* bqd1, const float* Wqd, const float* bqd, float* qd_t,
    const float* Es, const float* Wsd1, const float* bsd1, const float* Wsd, const float* bsd, float* sd_t)
{
  int blk = blockIdx.x;
  if (blk < NB_CORR) { corr_role(blk, Eq, Km, Wsa, bsa, corr_t, w2_t, csb_t); return; }
  blk -= NB_CORR;
  if (blk < NB_EA)   { ea_role(blk, Eqa, We, be, Wa, ba, eat2); return; }
  blk -= NB_EA;
  if (blk < NB_QD)   { mlp_role(blk, Eq, Wqd1, bqd1, Wqd, bqd, qd_t, NQR); return; }
  blk -= NB_QD;
  if (blk < NB_SD)   { mlp_role(blk, Es, Wsd1, bsd1, Wsd, bsd, sd_t, NSR); return; }
  blk -= NB_SD;
  pk_role(blk, q_data, qa_data, pkt);
}

// ---------------------------------------------------------------------------
// The sequential scan, v11: 4 m-rows/wave -> 4096 waves = 4 waves/SIMD on
// all 256 CUs (2 blocks/CU of 512 threads). Machine FMA work per step is
// unchanged (96 cyc/SIMD); per-wave tail is now tiny, and 4 resident waves
// fill each other's dependency stalls. eat2 {er,er,ad,ad} float4: one
// dwordx4 yields both packed-broadcast pairs (no v_movs). Packed q|qa,
// scalar corr s_loads, named-f2 packed FMA, E/O pipeline as v10.
// Block x of 8 waves: dq = x>>1, mh = x&1; wave w -> mg = mh*8+w (0..15),
// m0 = mg*4. Full-wave 6-DPP reduce -> 64 partials (final as v10).
// ---------------------------------------------------------------------------
static __device__ __forceinline__ int4 getpk(const int4& pk, int g) {
  int4 r;
  r.x = __builtin_amdgcn_readlane(pk.x, g);
  r.y = __builtin_amdgcn_readlane(pk.y, g);
  r.z = __builtin_amdgcn_readlane(pk.z, g);
  r.w = __builtin_amdgcn_readlane(pk.w, g);
  return r;
}
#define PQ(v)  ((v) & 0xffff)
#define PA(v)  ((int)(((unsigned)(v)) >> 16))

// one scan step on 4 rows (2 f2 pairs); returns UNREDUCED (r.x+r.y)*w2
static __device__ __forceinline__ float stepp(
    f2& Mv01, f2& Mv23, f2 c01, f2 c23, f2 er2, f2 ad2, float w2)
{
  f2 r = c01 * Mv01;
  f2 t0 = __builtin_elementwise_fma(er2, -Mv01, ad2);   // ad - er*Mv
  Mv01 = __builtin_elementwise_fma(c01, t0, Mv01);
  r = __builtin_elementwise_fma(c23, Mv23, r);
  f2 t1 = __builtin_elementwise_fma(er2, -Mv23, ad2);
  Mv23 = __builtin_elementwise_fma(c23, t1, Mv23);
  return (r.x + r.y) * w2;
}

// fetch corr rows (4 floats each) for the 4 steps of group P -> 8 named f2
#define FETCH_C(P) do { \
  const f2* _p0 = (const f2*)(corr_t + PQ((P).x) * M_ + m0); \
  const f2* _p1 = (const f2*)(corr_t + PQ((P).y) * M_ + m0); \
  const f2* _p2 = (const f2*)(corr_t + PQ((P).z) * M_ + m0); \
  const f2* _p3 = (const f2*)(corr_t + PQ((P).w) * M_ + m0); \
  c0_01=_p0[0]; c0_23=_p0[1]; \
  c1_01=_p1[0]; c1_23=_p1[1]; \
  c2_01=_p2[0]; c2_23=_p2[1]; \
  c3_01=_p3[0]; c3_23=_p3[1]; \
} while(0)

// fetch vector operands: eat2 dwordx4 -> {er2, ad2}; w2 scalar
#define FETCH_V(P, e0,a0,e1,a1,e2,a2,e3,a3, w0,w1,w2v,w3) do { \
  float4 _v0 = *(const float4*)(eat2 + (size_t)(PA((P).x) * DV_ + d) * 4); \
  float4 _v1 = *(const float4*)(eat2 + (size_t)(PA((P).y) * DV_ + d) * 4); \
  float4 _v2 = *(const float4*)(eat2 + (size_t)(PA((P).z) * DV_ + d) * 4); \
  float4 _v3 = *(const float4*)(eat2 + (size_t)(PA((P).w) * DV_ + d) * 4); \
  e0.x=_v0.x; e0.y=_v0.y; a0.x=_v0.z; a0.y=_v0.w; \
  e1.x=_v1.x; e1.y=_v1.y; a1.x=_v1.z; a1.y=_v1.w; \
  e2.x=_v2.x; e2.y=_v2.y; a2.x=_v2.z; a2.y=_v2.w; \
  e3.x=_v3.x; e3.y=_v3.y; a3.x=_v3.z; a3.y=_v3.w; \
  w0  = w2_t[PQ((P).x) * DV_ + d]; \
  w1  = w2_t[PQ((P).y) * DV_ + d]; \
  w2v = w2_t[PQ((P).z) * DV_ + d]; \
  w3  = w2_t[PQ((P).w) * DV_ + d]; \
} while(0)

__global__ __launch_bounds__(512) void scan_kernel(
    const int* __restrict__ pkt,
    const float* __restrict__ corr_t, const float* __restrict__ eat2,
    const float* __restrict__ w2_t,
    const float* __restrict__ Vm, float* __restrict__ sa_part)
{
  const int b   = blockIdx.y;
  const int x   = blockIdx.x;        // 0..7
  const int dq  = x >> 1;            // d chunk 0..3
  const int mh  = x & 1;
  const int tid = threadIdx.x;
  const int dl  = tid & 63;
  const int w   = tid >> 6;          // wave in block 0..7
  const int mg  = mh * 8 + w;        // m group 0..15 (4 rows each)
  const int m0  = __builtin_amdgcn_readfirstlane(mg * 4);
  const int d   = dq * 64 + dl;

  // per-lane packed q|qa: lane l holds t = 4l..4l+3
  const int4 pk = ((const int4*)(pkt + b * T_))[dl];

  f2 Mv01, Mv23;
  Mv01.x = Vm[(m0 + 0) * DV_ + d];  Mv01.y = Vm[(m0 + 1) * DV_ + d];
  Mv23.x = Vm[(m0 + 2) * DV_ + d];  Mv23.y = Vm[(m0 + 3) * DV_ + d];

  // partial layout: [p = dq*16 + mg][b][t], contiguous in t (64 partials)
  float* baseP = sa_part + ((dq * 16 + mg) * B_ + b) * T_;

  // named operand registers
  f2 c0_01, c0_23, c1_01, c1_23, c2_01, c2_23, c3_01, c3_23;
  f2 eE0, aE0, eE1, aE1, eE2, aE2, eE3, aE3;
  f2 eO0, aO0, eO1, aO1, eO2, aO2, eO3, aO3;
  float wE0, wE1, wE2, wE3, wO0, wO1, wO2, wO3;

  // -------- pipeline prologue --------
  int4 I0 = getpk(pk, 0);
  int4 I1 = getpk(pk, 1);
  FETCH_C(I0);                                                // c for group 0
  FETCH_V(I0, eE0,aE0,eE1,aE1,eE2,aE2,eE3,aE3, wE0,wE1,wE2,wE3); // grp 0 (even)
  FETCH_V(I1, eO0,aO0,eO1,aO1,eO2,aO2,eO3,aO3, wO0,wO1,wO2,wO3); // grp 1 (odd)
  int4 Icur = I1;                                             // c refill target
  int4 Inxt = getpk(pk, 2);                                   // vec refill target

  for (int g = 0; g < 64; g += 2) {
    // ---- group g (even) ----
    float s0 = stepp(Mv01, Mv23, c0_01, c0_23, eE0, aE0, wE0);
    float s1 = stepp(Mv01, Mv23, c1_01, c1_23, eE1, aE1, wE1);
    float s2 = stepp(Mv01, Mv23, c2_01, c2_23, eE2, aE2, wE2);
    float s3 = stepp(Mv01, Mv23, c3_01, c3_23, eE3, aE3, wE3);
    FETCH_C(Icur);                                              // c for g+1
    FETCH_V(Inxt, eE0,aE0,eE1,aE1,eE2,aE2,eE3,aE3, wE0,wE1,wE2,wE3); // vec g+2
    Icur = Inxt;
    Inxt = getpk(pk, (g + 3) & 63);
    float4 p;
    p.x = wave_sum_lane63(s0);
    p.y = wave_sum_lane63(s1);
    p.z = wave_sum_lane63(s2);
    p.w = wave_sum_lane63(s3);
    if (dl == 63) *(float4*)(baseP + 4 * g) = p;

    // ---- group g+1 (odd) ----
    s0 = stepp(Mv01, Mv23, c0_01, c0_23, eO0, aO0, wO0);
    s1 = stepp(Mv01, Mv23, c1_01, c1_23, eO1, aO1, wO1);
    s2 = stepp(Mv01, Mv23, c2_01, c2_23, eO2, aO2, wO2);
    s3 = stepp(Mv01, Mv23, c3_01, c3_23, eO3, aO3, wO3);
    FETCH_C(Icur);                                              // c for g+2
    FETCH_V(Inxt, eO0,aO0,eO1,aO1,eO2,aO2,eO3,aO3, wO0,wO1,wO2,wO3); // vec g+3
    Icur = Inxt;
    Inxt = getpk(pk, (g + 4) & 63);
    p.x = wave_sum_lane63(s0);
    p.y = wave_sum_lane63(s1);
    p.z = wave_sum_lane63(s2);
    p.w = wave_sum_lane63(s3);
    if (dl == 63) *(float4*)(baseP + 4 * g + 4) = p;
  }
}

// ---------------------------------------------------------------------------
// out[b,t] = sigmoid( 3*(sum of 64 sa partials + csb[q]) - qd[q] - sd[s] )
// sa_part layout: [p in 0..63][b][t] -> coalesced reads per p-slice.
// ---------------------------------------------------------------------------
__global__ __launch_bounds__(256) void final_kernel(
    const int* __restrict__ q_data, const int* __restrict__ s_data,
    const float* __restrict__ sa_part, const float* __restrict__ csb_t,
    const float* __restrict__ qd_t, const float* __restrict__ sd_t,
    float* __restrict__ out)
{
  const int b = blockIdx.x, t = threadIdx.x;
  float s = 0.f;
  #pragma unroll
  for (int p = 0; p < 64; ++p) s += sa_part[(p * B_ + b) * T_ + t];
  const int bt = b * T_ + t;
  const int q  = q_data[bt];
  const int si = s_data[bt];
  const float sa = s + csb_t[q];
  const float z = 3.f * sa - qd_t[q] - sd_t[si];
  out[bt] = 1.f / (1.f + __expf(-z));
}

// ---------------------------------------------------------------------------
extern "C" void kernel_launch(void* const* d_in, const int* in_sizes, int n_in,
                              void* d_out, int out_size, void* d_ws, size_t ws_size,
                              hipStream_t stream)
{
  const int*   q_data = (const int*)d_in[0];
  const int*   qa_data= (const int*)d_in[1];
  const int*   s_data = (const int*)d_in[2];
  const float* Km     = (const float*)d_in[3];
  const float* Vm     = (const float*)d_in[4];
  const float* Eq     = (const float*)d_in[5];
  const float* Eqa    = (const float*)d_in[6];
  const float* Es     = (const float*)d_in[7];
  const float* We     = (const float*)d_in[8];
  const float* be     = (const float*)d_in[9];
  const float* Wa     = (const float*)d_in[10];
  const float* ba     = (const float*)d_in[11];
  const float* Wsa    = (const float*)d_in[12];
  const float* bsa    = (const float*)d_in[13];
  const float* Wqd1   = (const float*)d_in[14];
  const float* bqd1   = (const float*)d_in[15];
  const float* Wqd    = (const float*)d_in[16];
  const float* bqd    = (const float*)d_in[17];
  const float* Wsd1   = (const float*)d_in[18];
  const float* bsd1   = (const float*)d_in[19];
  const float* Wsd    = (const float*)d_in[20];
  const float* bsd    = (const float*)d_in[21];
  float* out = (float*)d_out;

  // workspace layout (floats); total ~6.2 MB
  float* wsf    = (float*)d_ws;
  float* corr_t = wsf;                       // 201*64   = 12864
  float* w2_t   = corr_t + NQR * M_;         // 201*256  = 51456
  float* csb_t  = w2_t + NQR * DV_;          // 201 -> pad 204
  float* eat2   = csb_t + 204;               // 401*256*4 = 410624 {er,er,ad,ad}
  float* qd_t   = eat2 + NQAR * DV_ * 4;     // 201 -> pad 204
  float* sd_t   = qd_t + 204;                // 2001 -> pad 2004
  int*   pkt    = (int*)(sd_t + 2004);       // 64*256 = 16384 packed q|qa
  float* sa_p   = sd_t + 2004 + 16384;       // 64*64*256 = 1048576

  tables_kernel<<<NB_TOT, 256, 0, stream>>>(
      q_data, qa_data, pkt,
      Eq, Km, Wsa, bsa, corr_t, w2_t, csb_t,
      Eqa, We, be, Wa, ba, eat2,
      Wqd1, bqd1, Wqd, bqd, qd_t,
      Es, Wsd1, bsd1, Wsd, bsd, sd_t);
  scan_kernel<<<dim3(8, B_), 512, 0, stream>>>(pkt, corr_t, eat2, w2_t, Vm, sa_p);
  final_kernel<<<B_, 256, 0, stream>>>(q_data, s_data, sa_p, csb_t, qd_t, sd_t, out);
}

// Round 13
// 158.354 us; speedup vs baseline: 1.1428x; 1.1428x over previous
//
#include <hip/hip_runtime.h>
#include <math.h>

// DeepIRT forward. Dims from the reference:
#define B_   64
#define T_   256
#define M_   64
#define DK_  128
#define DV_  256
#define S_   128
#define NQR  201     // Eq rows  (q_data in [0,200])
#define NQAR 401     // Eqa rows (qa_data in [0,400])
#define NSR  2001    // Es rows  (s_data in [0,2000])

typedef float f2 __attribute__((ext_vector_type(2)));

static __device__ __forceinline__ int imin(int a, int b){ return a < b ? a : b; }

static __device__ __forceinline__ float fast_tanh(float x){
  float e = __expf(2.f * x);
  return 1.f - 2.f / (e + 1.f);
}

// ---------------------------------------------------------------------------
// DPP adds (GCNDPPCombine folds mov+add into v_add_f32_dpp).
// ---------------------------------------------------------------------------
template<int CTRL, int RM>
static __device__ __forceinline__ float dppadd(float x) {
  return x + __int_as_float(
      __builtin_amdgcn_update_dpp(0, __float_as_int(x), CTRL, RM, 0xf, true));
}
// full wave64 sum -> lane 63
static __device__ __forceinline__ float wave_sum_lane63(float x) {
  x = dppadd<0x111, 0xf>(x);
  x = dppadd<0x112, 0xf>(x);
  x = dppadd<0x114, 0xf>(x);
  x = dppadd<0x118, 0xf>(x);
  x = dppadd<0x142, 0xa>(x);  // row_bcast:15
  x = dppadd<0x143, 0xc>(x);  // row_bcast:31
  return x;
}
// 32-lane half-wave sums -> lane 31 (lanes 0-31) and lane 63 (lanes 32-63)
static __device__ __forceinline__ float half_sum_lane31_63(float x) {
  x = dppadd<0x111, 0xf>(x);
  x = dppadd<0x112, 0xf>(x);
  x = dppadd<0x114, 0xf>(x);
  x = dppadd<0x118, 0xf>(x);  // lanes 15/31/47/63 hold 16-sums
  x = dppadd<0x142, 0xa>(x);  // row_bcast:15 into rows 1,3 -> lanes 31,63
  return x;
}

// ---------------------------------------------------------------------------
// Role: corr row + fused w2/csb rows.  4 rows/block, 1 wave/row.
// ---------------------------------------------------------------------------
__device__ void corr_role(int blk, const float* __restrict__ Eq,
                          const float* __restrict__ Km,
                          const float* __restrict__ Wsa,
                          const float* __restrict__ bsa,
                          float* __restrict__ corr,
                          float* __restrict__ w2_t,
                          float* __restrict__ csb_t)
{
  __shared__ float eq[4][DK_];
  __shared__ float cwb[4][M_];
  const int w = threadIdx.x >> 6, m = threadIdx.x & 63;
  const int i  = blk * 4 + w;
  const int ic = imin(i, NQR - 1);
  eq[w][m]      = Eq[ic * DK_ + m];
  eq[w][m + 64] = Eq[ic * DK_ + 64 + m];
  float acc = 0.f;
  const float4* kr = (const float4*)(Km + m * DK_);
  #pragma unroll 8
  for (int k4 = 0; k4 < DK_ / 4; ++k4) {
    float4 kv = kr[k4];
    acc = fmaf(eq[w][k4 * 4 + 0], kv.x, acc);
    acc = fmaf(eq[w][k4 * 4 + 1], kv.y, acc);
    acc = fmaf(eq[w][k4 * 4 + 2], kv.z, acc);
    acc = fmaf(eq[w][k4 * 4 + 3], kv.w, acc);
  }
  float mx = acc;
  #pragma unroll
  for (int off = 32; off; off >>= 1) mx = fmaxf(mx, __shfl_xor(mx, off, 64));
  float e = __expf(acc - mx);
  float ssum = e;
  #pragma unroll
  for (int off = 32; off; off >>= 1) ssum += __shfl_xor(ssum, off, 64);
  const float cw = e / ssum;
  if (i < NQR) corr[i * M_ + m] = cw;
  cwb[w][m] = cw;

  float pv = wave_sum_lane63(cw * bsa[m]);
  if (m == 63 && i < NQR) csb_t[i] = pv;

  float aw[4] = {0,0,0,0};
  for (int mm4 = 0; mm4 < M_ / 4; ++mm4) {
    #pragma unroll
    for (int r = 0; r < 4; ++r) {
      float4 wv = *(const float4*)(Wsa + (r * 64 + m) * M_ + mm4 * 4);
      aw[r] = fmaf(cwb[w][mm4 * 4 + 0], wv.x, aw[r]);
      aw[r] = fmaf(cwb[w][mm4 * 4 + 1], wv.y, aw[r]);
      aw[r] = fmaf(cwb[w][mm4 * 4 + 2], wv.z, aw[r]);
      aw[r] = fmaf(cwb[w][mm4 * 4 + 3], wv.w, aw[r]);
    }
  }
  if (i < NQR) {
    #pragma unroll
    for (int r = 0; r < 4; ++r) w2_t[i * DV_ + r * 64 + m] = aw[r];
  }
}

// ---------------------------------------------------------------------------
// Role: erase/add tables, INTERLEAVED: eat[i][d] = {er, ad} (float2).
// ---------------------------------------------------------------------------
__device__ void ea_role(int blk, const float* __restrict__ Eqa,
                        const float* __restrict__ We, const float* __restrict__ be,
                        const float* __restrict__ Wa, const float* __restrict__ ba,
                        float* __restrict__ eat)
{
  __shared__ float a[8][DV_];
  const int d  = threadIdx.x;
  const int i0 = blk * 8;
  #pragma unroll
  for (int r = 0; r < 8; ++r) a[r][d] = Eqa[imin(i0 + r, NQAR - 1) * DV_ + d];
  __syncthreads();
  float er[8] = {0,0,0,0,0,0,0,0}, ad[8] = {0,0,0,0,0,0,0,0};
  for (int k = 0; k < DV_; ++k) {
    float we = We[k * DV_ + d];
    float wa = Wa[k * DV_ + d];
    #pragma unroll
    for (int r = 0; r < 8; ++r) {
      er[r] = fmaf(a[r][k], we, er[r]);
      ad[r] = fmaf(a[r][k], wa, ad[r]);
    }
  }
  const float beo = be[d], bao = ba[d];
  #pragma unroll
  for (int r = 0; r < 8; ++r) {
    int i = i0 + r;
    if (i < NQAR) {
      float2 v; v.x = er[r] + beo; v.y = ad[r] + bao;
      *(float2*)(eat + (size_t)(i * DV_ + d) * 2) = v;
    }
  }
}

// ---------------------------------------------------------------------------
// Role: tanh-MLP scalar tables.
// ---------------------------------------------------------------------------
__device__ void mlp_role(int blk, const float* __restrict__ E,
                         const float* __restrict__ W1, const float* __restrict__ b1,
                         const float* __restrict__ W2v, const float* __restrict__ b2,
                         float* __restrict__ outt, int nrows)
{
  __shared__ float e[8 * S_];
  __shared__ float red[8][2];
  const int tid = threadIdx.x;
  const int s = tid & 127, rh = tid >> 7;
  const int i0 = blk * 8;
  #pragma unroll
  for (int j = 0; j < 4; ++j) {
    int x = tid + j * 256;
    int row = imin(i0 + (x >> 7), nrows - 1);
    e[x] = E[row * DK_ + (x & 127)];
  }
  __syncthreads();
  float acc[4] = {0,0,0,0};
  const float* eb = e + rh * 4 * 128;
  for (int k = 0; k < DK_; ++k) {
    float wv = W1[k * S_ + s];
    #pragma unroll
    for (int r = 0; r < 4; ++r) acc[r] = fmaf(eb[r * 128 + k], wv, acc[r]);
  }
  const float b1s = b1[s], w2s = W2v[s];
  float p[4];
  #pragma unroll
  for (int r = 0; r < 4; ++r) p[r] = fast_tanh(acc[r] + b1s) * w2s;
  #pragma unroll
  for (int r = 0; r < 4; ++r) p[r] = wave_sum_lane63(p[r]);
  const int lane = tid & 63;
  const int half = s >> 6;
  if (lane == 63) {
    #pragma unroll
    for (int r = 0; r < 4; ++r) red[rh * 4 + r][half] = p[r];
  }
  __syncthreads();
  if (tid < 8) {
    int i = i0 + tid;
    if (i < nrows) outt[i] = red[tid][0] + red[tid][1] + b2[0];
  }
}

// ---------------------------------------------------------------------------
// Role: packed index table pk[b,t] = (qa<<16) | q.  16 blocks x 1024 vals.
// ---------------------------------------------------------------------------
__device__ void pk_role(int blk, const int* __restrict__ q,
                        const int* __restrict__ qa, int* __restrict__ pkt)
{
  const int i = (blk * 256 + threadIdx.x) * 4;
  int4 qv = *(const int4*)(q + i);
  int4 av = *(const int4*)(qa + i);
  int4 p;
  p.x = (av.x << 16) | qv.x;
  p.y = (av.y << 16) | qv.y;
  p.z = (av.z << 16) | qv.z;
  p.w = (av.w << 16) | qv.w;
  *(int4*)(pkt + i) = p;
}

// ---------------------------------------------------------------------------
#define NB_CORR 51
#define NB_EA   51
#define NB_QD   26
#define NB_SD   251
#define NB_PK   16
#define NB_TOT  (NB_CORR + NB_EA + NB_QD + NB_SD + NB_PK)

__global__ __launch_bounds__(256) void tables_kernel(
    const int* q_data, const int* qa_data, int* pkt,
    const float* Eq, const float* Km, const float* Wsa, const float* bsa,
    float* corr_t, float* w2_t, float* csb_t,
    const float* Eqa, const float* We, const float* be,
    const float* Wa, const float* ba, float* eat,
    const float* Wqd1, const float* bqd1, const float* Wqd, const float* bqd, float* qd_t,
    const float* Es, const float* Wsd1, const float* bsd1, const float* Wsd, const float* bsd, float* sd_t)
{
  int blk = blockIdx.x;
  if (blk < NB_CORR) { corr_role(blk, Eq, Km, Wsa, bsa, corr_t, w2_t, csb_t); return; }
  blk -= NB_CORR;
  if (blk < NB_EA)   { ea_role(blk, Eqa, We, be, Wa, ba, eat); return; }
  blk -= NB_EA;
  if (blk < NB_QD)   { mlp_role(blk, Eq, Wqd1, bqd1, Wqd, bqd, qd_t, NQR); return; }
  blk -= NB_QD;
  if (blk < NB_SD)   { mlp_role(blk, Es, Wsd1, bsd1, Wsd, bsd, sd_t, NSR); return; }
  blk -= NB_SD;
  pk_role(blk, q_data, qa_data, pkt);
}

// ---------------------------------------------------------------------------
// The sequential scan, v13 = v12 (resubmitted after a transient post-timing
// failure; numerically identical to v10 which passed): 8 m-rows/wave,
// 2048 waves = 2/SIMD on all 256 CUs, packed q|qa, scalar corr s_loads,
// float2 eat, named-f2 packed FMA, E/O pipeline, saddr-form vector
// addressing (scalar row base + hoisted per-lane offset).
// ---------------------------------------------------------------------------
static __device__ __forceinline__ int4 getpk(const int4& pk, int g) {
  int4 r;
  r.x = __builtin_amdgcn_readlane(pk.x, g);
  r.y = __builtin_amdgcn_readlane(pk.y, g);
  r.z = __builtin_amdgcn_readlane(pk.z, g);
  r.w = __builtin_amdgcn_readlane(pk.w, g);
  return r;
}
#define PQ(v)  ((v) & 0xffff)
#define PA(v)  ((int)(((unsigned)(v)) >> 16))

// one scan step on 8 rows held as 4 f2 pairs; returns UNREDUCED (r.x+r.y)*w2
static __device__ __forceinline__ float stepp(
    f2& Mv01, f2& Mv23, f2& Mv45, f2& Mv67,
    f2 c01, f2 c23, f2 c45, f2 c67, f2 ea, float w2)
{
  f2 er2; er2.x = ea.x; er2.y = ea.x;   // broadcast er (op_sel-able)
  f2 ad2; ad2.x = ea.y; ad2.y = ea.y;   // broadcast ad
  f2 r = c01 * Mv01;
  f2 t0 = __builtin_elementwise_fma(er2, -Mv01, ad2);   // ad - er*Mv
  Mv01 = __builtin_elementwise_fma(c01, t0, Mv01);
  r = __builtin_elementwise_fma(c23, Mv23, r);
  f2 t1 = __builtin_elementwise_fma(er2, -Mv23, ad2);
  Mv23 = __builtin_elementwise_fma(c23, t1, Mv23);
  r = __builtin_elementwise_fma(c45, Mv45, r);
  f2 t2 = __builtin_elementwise_fma(er2, -Mv45, ad2);
  Mv45 = __builtin_elementwise_fma(c45, t2, Mv45);
  r = __builtin_elementwise_fma(c67, Mv67, r);
  f2 t3 = __builtin_elementwise_fma(er2, -Mv67, ad2);
  Mv67 = __builtin_elementwise_fma(c67, t3, Mv67);
  return (r.x + r.y) * w2;
}

// fetch corr rows (8 floats each) for the 4 steps of group P -> 16 named f2
#define FETCH_C(P) do { \
  const f2* _p0 = (const f2*)(corr_t + PQ((P).x) * M_ + m0); \
  const f2* _p1 = (const f2*)(corr_t + PQ((P).y) * M_ + m0); \
  const f2* _p2 = (const f2*)(corr_t + PQ((P).z) * M_ + m0); \
  const f2* _p3 = (const f2*)(corr_t + PQ((P).w) * M_ + m0); \
  c0_01=_p0[0]; c0_23=_p0[1]; c0_45=_p0[2]; c0_67=_p0[3]; \
  c1_01=_p1[0]; c1_23=_p1[1]; c1_45=_p1[2]; c1_67=_p1[3]; \
  c2_01=_p2[0]; c2_23=_p2[1]; c2_45=_p2[2]; c2_67=_p2[3]; \
  c3_01=_p3[0]; c3_23=_p3[1]; c3_45=_p3[2]; c3_67=_p3[3]; \
} while(0)

// fetch vector operands with scalar base + fixed per-lane offset (saddr form)
#define FETCH_V(P, ea0,ea1,ea2,ea3, w0,w1,w2v,w3) do { \
  const float* _e0 = eat + (size_t)PA((P).x) * (DV_ * 2); \
  const float* _e1 = eat + (size_t)PA((P).y) * (DV_ * 2); \
  const float* _e2 = eat + (size_t)PA((P).z) * (DV_ * 2); \
  const float* _e3 = eat + (size_t)PA((P).w) * (DV_ * 2); \
  ea0 = *(const f2*)(_e0 + d2); \
  ea1 = *(const f2*)(_e1 + d2); \
  ea2 = *(const f2*)(_e2 + d2); \
  ea3 = *(const f2*)(_e3 + d2); \
  const float* _w0 = w2_t + PQ((P).x) * DV_; \
  const float* _w1 = w2_t + PQ((P).y) * DV_; \
  const float* _w2 = w2_t + PQ((P).z) * DV_; \
  const float* _w3 = w2_t + PQ((P).w) * DV_; \
  w0  = _w0[d]; \
  w1  = _w1[d]; \
  w2v = _w2[d]; \
  w3  = _w3[d]; \
} while(0)

__global__ __launch_bounds__(512) void scan_kernel(
    const int* __restrict__ pkt,
    const float* __restrict__ corr_t, const float* __restrict__ eat,
    const float* __restrict__ w2_t,
    const float* __restrict__ Vm, float* __restrict__ sa_part)
{
  const int b   = blockIdx.y;
  const int dq  = blockIdx.x;        // 0..3, one d-chunk per block (L1 reuse)
  const int tid = threadIdx.x;
  const int dl  = tid & 63;
  const int mg  = tid >> 6;          // wave in block = m-group 0..7
  const int m0  = __builtin_amdgcn_readfirstlane(mg * 8);
  const int d   = dq * 64 + dl;
  const int d2  = d * 2;             // hoisted per-lane offset for eat
  const int half = dl >> 5;          // 32-lane half 0..1

  // per-lane packed q|qa: lane l holds t = 4l..4l+3
  const int4 pk = ((const int4*)(pkt + b * T_))[dl];

  f2 Mv01, Mv23, Mv45, Mv67;
  Mv01.x = Vm[(m0 + 0) * DV_ + d];  Mv01.y = Vm[(m0 + 1) * DV_ + d];
  Mv23.x = Vm[(m0 + 2) * DV_ + d];  Mv23.y = Vm[(m0 + 3) * DV_ + d];
  Mv45.x = Vm[(m0 + 4) * DV_ + d];  Mv45.y = Vm[(m0 + 5) * DV_ + d];
  Mv67.x = Vm[(m0 + 6) * DV_ + d];  Mv67.y = Vm[(m0 + 7) * DV_ + d];

  // partial layout: [p = dq*16 + mg*2 + half][b][t], contiguous in t
  float* baseP = sa_part + ((dq * 16 + mg * 2 + half) * B_ + b) * T_;

  // named operand registers
  f2 c0_01, c0_23, c0_45, c0_67;
  f2 c1_01, c1_23, c1_45, c1_67;
  f2 c2_01, c2_23, c2_45, c2_67;
  f2 c3_01, c3_23, c3_45, c3_67;
  f2 eE0, eE1, eE2, eE3, eO0, eO1, eO2, eO3;
  float wE0, wE1, wE2, wE3, wO0, wO1, wO2, wO3;

  // -------- pipeline prologue --------
  int4 I0 = getpk(pk, 0);
  int4 I1 = getpk(pk, 1);
  FETCH_C(I0);                                  // c for group 0
  FETCH_V(I0, eE0,eE1,eE2,eE3, wE0,wE1,wE2,wE3); // vec for group 0 (even)
  FETCH_V(I1, eO0,eO1,eO2,eO3, wO0,wO1,wO2,wO3); // vec for group 1 (odd)
  int4 Icur = I1;                               // c refill target
  int4 Inxt = getpk(pk, 2);                     // vec refill target

  for (int g = 0; g < 64; g += 2) {
    // ---- group g (even): c holds group g, eE/wE hold group g ----
    float s0 = stepp(Mv01,Mv23,Mv45,Mv67, c0_01,c0_23,c0_45,c0_67, eE0, wE0);
    float s1 = stepp(Mv01,Mv23,Mv45,Mv67, c1_01,c1_23,c1_45,c1_67, eE1, wE1);
    float s2 = stepp(Mv01,Mv23,Mv45,Mv67, c2_01,c2_23,c2_45,c2_67, eE2, wE2);
    float s3 = stepp(Mv01,Mv23,Mv45,Mv67, c3_01,c3_23,c3_45,c3_67, eE3, wE3);
    FETCH_C(Icur);                                    // c for group g+1
    FETCH_V(Inxt, eE0,eE1,eE2,eE3, wE0,wE1,wE2,wE3);  // vec for group g+2
    Icur = Inxt;
    Inxt = getpk(pk, (g + 3) & 63);
    // batched reduces: 4 independent 5-level DPP chains interleave
    float4 p;
    p.x = half_sum_lane31_63(s0);
    p.y = half_sum_lane31_63(s1);
    p.z = half_sum_lane31_63(s2);
    p.w = half_sum_lane31_63(s3);
    if ((dl & 31) == 31) *(float4*)(baseP + 4 * g) = p;

    // ---- group g+1 (odd): c holds group g+1, eO/wO hold group g+1 ----
    s0 = stepp(Mv01,Mv23,Mv45,Mv67, c0_01,c0_23,c0_45,c0_67, eO0, wO0);
    s1 = stepp(Mv01,Mv23,Mv45,Mv67, c1_01,c1_23,c1_45,c1_67, eO1, wO1);
    s2 = stepp(Mv01,Mv23,Mv45,Mv67, c2_01,c2_23,c2_45,c2_67, eO2, wO2);
    s3 = stepp(Mv01,Mv23,Mv45,Mv67, c3_01,c3_23,c3_45,c3_67, eO3, wO3);
    FETCH_C(Icur);                                    // c for group g+2
    FETCH_V(Inxt, eO0,eO1,eO2,eO3, wO0,wO1,wO2,wO3);  // vec for group g+3
    Icur = Inxt;
    Inxt = getpk(pk, (g + 4) & 63);
    p.x = half_sum_lane31_63(s0);
    p.y = half_sum_lane31_63(s1);
    p.z = half_sum_lane31_63(s2);
    p.w = half_sum_lane31_63(s3);
    if ((dl & 31) == 31) *(float4*)(baseP + 4 * g + 4) = p;
  }
}

// ---------------------------------------------------------------------------
// out[b,t] = sigmoid( 3*(sum of 64 sa partials + csb[q]) - qd[q] - sd[s] )
// sa_part layout: [p in 0..63][b][t] -> coalesced reads per p-slice.
// ---------------------------------------------------------------------------
__global__ __launch_bounds__(256) void final_kernel(
    const int* __restrict__ q_data, const int* __restrict__ s_data,
    const float* __restrict__ sa_part, const float* __restrict__ csb_t,
    const float* __restrict__ qd_t, const float* __restrict__ sd_t,
    float* __restrict__ out)
{
  const int b = blockIdx.x, t = threadIdx.x;
  float s = 0.f;
  #pragma unroll
  for (int p = 0; p < 64; ++p) s += sa_part[(p * B_ + b) * T_ + t];
  const int bt = b * T_ + t;
  const int q  = q_data[bt];
  const int si = s_data[bt];
  const float sa = s + csb_t[q];
  const float z = 3.f * sa - qd_t[q] - sd_t[si];
  out[bt] = 1.f / (1.f + __expf(-z));
}

// ---------------------------------------------------------------------------
extern "C" void kernel_launch(void* const* d_in, const int* in_sizes, int n_in,
                              void* d_out, int out_size, void* d_ws, size_t ws_size,
                              hipStream_t stream)
{
  const int*   q_data = (const int*)d_in[0];
  const int*   qa_data= (const int*)d_in[1];
  const int*   s_data = (const int*)d_in[2];
  const float* Km     = (const float*)d_in[3];
  const float* Vm     = (const float*)d_in[4];
  const float* Eq     = (const float*)d_in[5];
  const float* Eqa    = (const float*)d_in[6];
  const float* Es     = (const float*)d_in[7];
  const float* We     = (const float*)d_in[8];
  const float* be     = (const float*)d_in[9];
  const float* Wa     = (const float*)d_in[10];
  const float* ba     = (const float*)d_in[11];
  const float* Wsa    = (const float*)d_in[12];
  const float* bsa    = (const float*)d_in[13];
  const float* Wqd1   = (const float*)d_in[14];
  const float* bqd1   = (const float*)d_in[15];
  const float* Wqd    = (const float*)d_in[16];
  const float* bqd    = (const float*)d_in[17];
  const float* Wsd1   = (const float*)d_in[18];
  const float* bsd1   = (const float*)d_in[19];
  const float* Wsd    = (const float*)d_in[20];
  const float* bsd    = (const float*)d_in[21];
  float* out = (float*)d_out;

  // workspace layout (floats); total ~5.6 MB
  float* wsf    = (float*)d_ws;
  float* corr_t = wsf;                       // 201*64   = 12864
  float* w2_t   = corr_t + NQR * M_;         // 201*256  = 51456
  float* csb_t  = w2_t + NQR * DV_;          // 201 -> pad 204
  float* eat    = csb_t + 204;               // 401*256*2 = 205312 (interleaved er/ad)
  float* qd_t   = eat + NQAR * DV_ * 2;      // 201 -> pad 204
  float* sd_t   = qd_t + 204;                // 2001 -> pad 2004
  int*   pkt    = (int*)(sd_t + 2004);       // 64*256 = 16384 packed q|qa
  float* sa_p   = sd_t + 2004 + 16384;       // 64*64*256 = 1048576

  tables_kernel<<<NB_TOT, 256, 0, stream>>>(
      q_data, qa_data, pkt,
      Eq, Km, Wsa, bsa, corr_t, w2_t, csb_t,
      Eqa, We, be, Wa, ba, eat,
      Wqd1, bqd1, Wqd, bqd, qd_t,
      Es, Wsd1, bsd1, Wsd, bsd, sd_t);
  scan_kernel<<<dim3(4, B_), 512, 0, stream>>>(pkt, corr_t, eat, w2_t, Vm, sa_p);
  final_kernel<<<B_, 256, 0, stream>>>(q_data, s_data, sa_p, csb_t, qd_t, sd_t, out);
}